// Round 5
// baseline (142.469 us; speedup 1.0000x reference)
//
#include <hip/hip_runtime.h>

#define NROW 8192
#define NF   128

typedef float f32x4  __attribute__((ext_vector_type(4)));
typedef int   i32x4  __attribute__((ext_vector_type(4)));
typedef short bf16x8 __attribute__((ext_vector_type(8)));
typedef short bf16x4 __attribute__((ext_vector_type(4)));

__device__ __forceinline__ short f2bf(float f) {
    union { float f; unsigned u; } v; v.f = f;
    unsigned r = v.u + 0x7FFFu + ((v.u >> 16) & 1u);
    return (short)(r >> 16);
}

// Tiled B layout: element (f, r) ->
//   (r>>6)*8192 + (f>>4)*1024 + ((r>>5)&1)*512 + (f&15)*32 + ((r>>3)&3)*8 + (r&7)
// so a B-fragment load (ct, half) is 64 lanes x 16B covering a contiguous 1KB.

// k0: WT[c][k] = bf16(W[k][c])   (128x128, tiny)
__global__ __launch_bounds__(256) void k0_wt(const float* __restrict__ W,
                                             short* __restrict__ WT) {
    int idx = blockIdx.x * 256 + threadIdx.x;
    int c = idx >> 7, k = idx & 127;
    WT[c * NF + k] = f2bf(W[k * NF + c]);
}

// k1: Wh = mo @ W via bf16 MFMA; writes WhT in the TILED layout above,
//     s1 = Wh@a1, s2 = Wh@a2 (f32).
__global__ __launch_bounds__(256) void k1_wh(const float* __restrict__ mo,
        const short* __restrict__ WT,
        const float* __restrict__ a1, const float* __restrict__ a2,
        short* __restrict__ WhT, float* __restrict__ s1g, float* __restrict__ s2g) {
    __shared__ float s_lds[2][32];
    int t = threadIdx.x;
    int w = t >> 6, l = t & 63, lg = l >> 4, lr = l & 15;
    int rows0 = blockIdx.x * 32;
    if (t < 64) s_lds[t >> 5][t & 31] = 0.0f;
    __syncthreads();

    f32x4 acc[2][2] = {}; // [rt][ct]
#pragma unroll
    for (int ks = 0; ks < 4; ++ks) {
        bf16x8 a[2], b[2];
#pragma unroll
        for (int rt = 0; rt < 2; ++rt) {
            const float* ap = mo + (size_t)(rows0 + rt*16 + lr) * NF + ks*32 + lg*8;
            f32x4 x0 = *(const f32x4*)ap;
            f32x4 x1 = *(const f32x4*)(ap + 4);
#pragma unroll
            for (int e = 0; e < 4; ++e) { a[rt][e] = f2bf(x0[e]); a[rt][4+e] = f2bf(x1[e]); }
        }
#pragma unroll
        for (int ct = 0; ct < 2; ++ct) {
            int c = w*32 + ct*16 + lr;
            b[ct] = *(const bf16x8*)(WT + c*NF + ks*32 + lg*8);
        }
#pragma unroll
        for (int rt = 0; rt < 2; ++rt)
#pragma unroll
            for (int ct = 0; ct < 2; ++ct)
                acc[rt][ct] = __builtin_amdgcn_mfma_f32_16x16x32_bf16(a[rt], b[ct], acc[rt][ct], 0, 0, 0);
    }

    // epilogue: C/D layout: col = lane&15, row = (lane>>4)*4 + reg
#pragma unroll
    for (int rt = 0; rt < 2; ++rt) {
        float p1[4] = {0,0,0,0}, p2[4] = {0,0,0,0};
#pragma unroll
        for (int ct = 0; ct < 2; ++ct) {
            int c = w*32 + ct*16 + lr;
            float a1c = a1[c], a2c = a2[c];
            bf16x4 wv;
#pragma unroll
            for (int g = 0; g < 4; ++g) {
                float v = acc[rt][ct][g];
                wv[g] = f2bf(v);
                p1[g] += v * a1c;
                p2[g] += v * a2c;
            }
            int r0 = rows0 + rt*16 + lg*4;
            size_t off = (size_t)(r0 >> 6) * 8192 + (size_t)(c >> 4) * 1024
                       + (size_t)((r0 >> 5) & 1) * 512 + (size_t)(c & 15) * 32
                       + (size_t)((r0 >> 3) & 3) * 8 + (size_t)(r0 & 7);
            *(bf16x4*)(WhT + off) = wv;
        }
#pragma unroll
        for (int off = 1; off < 16; off <<= 1) {
#pragma unroll
            for (int g = 0; g < 4; ++g) {
                p1[g] += __shfl_xor(p1[g], off);
                p2[g] += __shfl_xor(p2[g], off);
            }
        }
        if (lr == 0) {
            int rloc = rt*16 + lg*4;
#pragma unroll
            for (int g = 0; g < 4; ++g) {
                atomicAdd(&s_lds[0][rloc+g], p1[g]);
                atomicAdd(&s_lds[1][rloc+g], p2[g]);
            }
        }
    }
    __syncthreads();
    if (t < 32)       s1g[rows0 + t]        = s_lds[0][t];
    else if (t < 64)  s2g[rows0 + (t - 32)] = s_lds[1][t - 32];
}

// k2: block = 4 waves on the SAME 16 rows, in-block j-split x4, cross-block x S.
// Unroll-2 main loop, adj prefetched DEPTH 2 (A0/A1 register sets): tile t's
// regs are refilled with tile t+2 right after t's exp consumes them, giving
// ~1300 cycles of issue-to-use cover (> ~900cy HBM latency). B tile is 16
// coalesced 1KB loads from the tiled WhT layout. No barriers in the main loop.
__global__ __launch_bounds__(256, 3) void k2_main(
        const int* __restrict__ adj, const short* __restrict__ WhT,
        const float* __restrict__ s1g, const float* __restrict__ s2g,
        float* __restrict__ numP, float* __restrict__ zP,
        int S, int npb) {
    __shared__ __attribute__((aligned(16))) char smem[18432 + 8192 + 64];
    short* Pl   = (short*)smem;                   // [4][2][16][72]
    float* Lacc = (float*)smem;                   // [2][2048], aliases Pl
    float* s2l  = (float*)(smem + 18432);         // [2048] block's s2 slice
    float* Lz   = (float*)(smem + 18432 + 8192);  // [16]
#define PL(W_,D_,R_) (Pl + (((W_)*2 + (D_))*16 + (R_))*72)

    int t = threadIdx.x, w = t >> 6, l = t & 63;
    int lo = l & 15, hi = l >> 4;     // used for both stage and fragment sides
    int b = blockIdx.x, jseg = b % S, rg = b / S;
    int rows0 = rg << 4;
    int j0 = jseg * npb;

    // stage s2 slice + init Lz
    { f32x4* d_ = (f32x4*)s2l; const f32x4* s_ = (const f32x4*)(s2g + j0);
      d_[t] = s_[t]; d_[t + 256] = s_[t + 256]; }
    if (t < 16) Lz[t] = 0.0f;
    __syncthreads();

    int nwt = npb >> 2;               // j span per wave
    int jb  = j0 + w * nwt;
    int NT  = nwt >> 6;               // = 8 (even)

    float s1q[4];
#pragma unroll
    for (int c = 0; c < 4; ++c) s1q[c] = s1g[rows0 + c*4 + hi];

    f32x4 acc[8] = {};
    float zacc[4] = {0.f, 0.f, 0.f, 0.f};

    // adj stage layout: instr c reads rows rows0+c*4+hi, cols jt+lo*4
    const int* abase = adj + (size_t)rows0 * NROW + lo*4;
#define AROW(C_) (abase + (size_t)((C_)*4 + hi) * NROW)

    i32x4 A0[4], A1[4];
#pragma unroll
    for (int c = 0; c < 4; ++c) {
        A0[c] = __builtin_nontemporal_load((const i32x4*)(AROW(c) + jb));
        A1[c] = __builtin_nontemporal_load((const i32x4*)(AROW(c) + jb + 64));
    }

#define TILE(AR_, D_, JT_, PF_) do { \
    const short* tb_ = WhT + (size_t)((JT_) >> 6) * 8192 + lo*32 + hi*8; \
    bf16x8 Bv_[8][2]; \
_Pragma("unroll") \
    for (int ct = 0; ct < 8; ++ct) { \
        Bv_[ct][0] = *(const bf16x8*)(tb_ + ct*1024); \
        Bv_[ct][1] = *(const bf16x8*)(tb_ + ct*1024 + 512); \
    } \
    f32x4 sv_ = *(const f32x4*)(s2l + ((JT_) - j0) + lo*4); \
_Pragma("unroll") \
    for (int c = 0; c < 4; ++c) { \
        bf16x4 pv_; \
_Pragma("unroll") \
        for (int e = 0; e < 4; ++e) { \
            float x_  = s1q[c] + sv_[e]; \
            float lk_ = fmaxf(x_, 0.2f * x_); \
            float p_  = __expf(lk_); \
            p_ = (AR_[c][e] > 0) ? p_ : 0.0f; \
            zacc[c] += p_; \
            pv_[e] = f2bf(p_); \
        } \
        if (PF_) AR_[c] = __builtin_nontemporal_load((const i32x4*)(AROW(c) + (JT_) + 128)); \
        *(bf16x4*)(PL(w, D_, c*4 + hi) + lo*4) = pv_; \
    } \
    const short* Pr_ = PL(w, D_, lo); \
    bf16x8 fa0_ = *(const bf16x8*)(Pr_ + hi*8); \
    bf16x8 fa1_ = *(const bf16x8*)(Pr_ + 32 + hi*8); \
_Pragma("unroll") \
    for (int ct = 0; ct < 8; ++ct) { \
        acc[ct] = __builtin_amdgcn_mfma_f32_16x16x32_bf16(fa0_, Bv_[ct][0], acc[ct], 0, 0, 0); \
        acc[ct] = __builtin_amdgcn_mfma_f32_16x16x32_bf16(fa1_, Bv_[ct][1], acc[ct], 0, 0, 0); \
    } \
} while (0)

    for (int it = 0; it < NT; it += 2) {
        int jt0 = jb + (it << 6);
        TILE(A0, 0, jt0,      it + 2 < NT);
        TILE(A1, 1, jt0 + 64, it + 3 < NT);
    }
#undef TILE
#undef AROW

    // --- z: reduce over the 16 lo-lanes (cols), rows = c*4+hi ---
#pragma unroll
    for (int c = 0; c < 4; ++c) {
        zacc[c] += __shfl_xor(zacc[c], 1);
        zacc[c] += __shfl_xor(zacc[c], 2);
        zacc[c] += __shfl_xor(zacc[c], 4);
        zacc[c] += __shfl_xor(zacc[c], 8);
    }
    if (lo == 0) {
#pragma unroll
        for (int c = 0; c < 4; ++c) atomicAdd(&Lz[c*4 + hi], zacc[c]);
    }
    __syncthreads();   // also separates last Pl reads from Lacc writes (alias!)
    if (t < 16) zP[(size_t)jseg * NROW + rows0 + t] = Lz[t];

    // --- acc: tree-reduce 4 waves (identical (lane,ct,g)->(row,col) maps) ---
    if (w >= 2) {
        float* s0 = &Lacc[(w - 2) * 2048];
#pragma unroll
        for (int ct = 0; ct < 8; ++ct) *(f32x4*)(s0 + ct*256 + l*4) = acc[ct];
    }
    __syncthreads();
    if (w < 2) {
        const float* s0 = &Lacc[w * 2048];
#pragma unroll
        for (int ct = 0; ct < 8; ++ct) acc[ct] += *(const f32x4*)(s0 + ct*256 + l*4);
    }
    __syncthreads();
    if (w == 1) {
        float* s0 = &Lacc[0];
#pragma unroll
        for (int ct = 0; ct < 8; ++ct) *(f32x4*)(s0 + ct*256 + l*4) = acc[ct];
    }
    __syncthreads();
    if (w == 0) {
        const float* s0 = &Lacc[0];
        size_t obase = (size_t)jseg * NROW * NF;
#pragma unroll
        for (int ct = 0; ct < 8; ++ct) {
            acc[ct] += *(const f32x4*)(s0 + ct*256 + l*4);
            int cc = ct*16 + lo;
            int r0 = rows0 + hi*4;
#pragma unroll
            for (int g = 0; g < 4; ++g)
                numP[obase + (size_t)(r0 + g) * NF + cc] = acc[ct][g];
        }
    }
#undef PL
}

// k3: out = elu( sum_s num / sum_s z ), vectorized x4
__global__ __launch_bounds__(256) void k3_reduce(const float* __restrict__ numP,
        const float* __restrict__ zP, float* __restrict__ out, int S) {
    int idx = (blockIdx.x * 256 + threadIdx.x) * 4;
    int r = idx >> 7;
    f32x4 num = {};
    float zz = 0.0f;
    for (int s = 0; s < S; ++s) {
        f32x4 v = *(const f32x4*)(numP + (size_t)s * (NROW * NF) + idx);
        num += v;
        zz  += zP[s * NROW + r];
    }
    f32x4 o;
#pragma unroll
    for (int e = 0; e < 4; ++e) {
        float h = num[e] / zz;
        o[e] = (h > 0.0f) ? h : expm1f(h);
    }
    *(f32x4*)(out + idx) = o;
}

extern "C" void kernel_launch(void* const* d_in, const int* in_sizes, int n_in,
                              void* d_out, int out_size, void* d_ws, size_t ws_size,
                              hipStream_t stream) {
    const float* mo  = (const float*)d_in[0];
    const int*   adj = (const int*)d_in[1];
    const float* W   = (const float*)d_in[2];
    const float* a1  = (const float*)d_in[3];
    const float* a2  = (const float*)d_in[4];
    float* out = (float*)d_out;

    char* p = (char*)d_ws;
    short* WT  = (short*)p;  p += (size_t)NF * NF * 2;
    short* WhT = (short*)p;  p += (size_t)NF * NROW * 2;
    float* s1  = (float*)p;  p += (size_t)NROW * 4;
    float* s2  = (float*)p;  p += (size_t)NROW * 4;
    float* zP  = (float*)p;  p += (size_t)4 * NROW * 4;   // reserved for S<=4
    size_t fixed = (size_t)(p - (char*)d_ws);

    int S = 4;
    while (S > 1 && fixed + (size_t)S * NROW * NF * 4 > ws_size) S >>= 1;
    float* numP = (float*)p;
    if (fixed + (size_t)S * NROW * NF * 4 > ws_size) numP = out;  // S==1 in-place fallback

    k0_wt<<<dim3(64), dim3(256), 0, stream>>>(W, WT);
    k1_wh<<<dim3(256), dim3(256), 0, stream>>>(mo, WT, a1, a2, WhT, s1, s2);
    k2_main<<<dim3((NROW / 16) * S), dim3(256), 0, stream>>>(adj, WhT, s1, s2, numP, zP, S, NROW / S);
    k3_reduce<<<dim3(NROW * NF / 1024), dim3(256), 0, stream>>>(numP, zP, out, S);
}

// Round 6
// 115.039 us; speedup vs baseline: 1.2384x; 1.2384x over previous
//
#include <hip/hip_runtime.h>

#define NROW 8192
#define NF   128

typedef float f32x4  __attribute__((ext_vector_type(4)));
typedef int   i32x4  __attribute__((ext_vector_type(4)));
typedef short bf16x8 __attribute__((ext_vector_type(8)));
typedef short bf16x4 __attribute__((ext_vector_type(4)));

__device__ __forceinline__ short f2bf(float f) {
    union { float f; unsigned u; } v; v.f = f;
    unsigned r = v.u + 0x7FFFu + ((v.u >> 16) & 1u);
    return (short)(r >> 16);
}

// Tiled B layout: element (f, r) ->
//   (r>>6)*8192 + (f>>4)*1024 + ((r>>5)&1)*512 + (f&15)*32 + ((r>>3)&3)*8 + (r&7)
// so a B-fragment load (ct, half) is 64 lanes x 16B covering a contiguous 1KB.

// k0: WT[c][k] = bf16(W[k][c])   (128x128, tiny)
__global__ __launch_bounds__(256) void k0_wt(const float* __restrict__ W,
                                             short* __restrict__ WT) {
    int idx = blockIdx.x * 256 + threadIdx.x;
    int c = idx >> 7, k = idx & 127;
    WT[c * NF + k] = f2bf(W[k * NF + c]);
}

// k1: Wh = mo @ W via bf16 MFMA; writes WhT in the TILED layout above,
//     s1 = Wh@a1, s2 = Wh@a2 (f32).
__global__ __launch_bounds__(256) void k1_wh(const float* __restrict__ mo,
        const short* __restrict__ WT,
        const float* __restrict__ a1, const float* __restrict__ a2,
        short* __restrict__ WhT, float* __restrict__ s1g, float* __restrict__ s2g) {
    __shared__ float s_lds[2][32];
    int t = threadIdx.x;
    int w = t >> 6, l = t & 63, lg = l >> 4, lr = l & 15;
    int rows0 = blockIdx.x * 32;
    if (t < 64) s_lds[t >> 5][t & 31] = 0.0f;
    __syncthreads();

    f32x4 acc[2][2] = {}; // [rt][ct]
#pragma unroll
    for (int ks = 0; ks < 4; ++ks) {
        bf16x8 a[2], b[2];
#pragma unroll
        for (int rt = 0; rt < 2; ++rt) {
            const float* ap = mo + (size_t)(rows0 + rt*16 + lr) * NF + ks*32 + lg*8;
            f32x4 x0 = *(const f32x4*)ap;
            f32x4 x1 = *(const f32x4*)(ap + 4);
#pragma unroll
            for (int e = 0; e < 4; ++e) { a[rt][e] = f2bf(x0[e]); a[rt][4+e] = f2bf(x1[e]); }
        }
#pragma unroll
        for (int ct = 0; ct < 2; ++ct) {
            int c = w*32 + ct*16 + lr;
            b[ct] = *(const bf16x8*)(WT + c*NF + ks*32 + lg*8);
        }
#pragma unroll
        for (int rt = 0; rt < 2; ++rt)
#pragma unroll
            for (int ct = 0; ct < 2; ++ct)
                acc[rt][ct] = __builtin_amdgcn_mfma_f32_16x16x32_bf16(a[rt], b[ct], acc[rt][ct], 0, 0, 0);
    }

    // epilogue: C/D layout: col = lane&15, row = (lane>>4)*4 + reg
#pragma unroll
    for (int rt = 0; rt < 2; ++rt) {
        float p1[4] = {0,0,0,0}, p2[4] = {0,0,0,0};
#pragma unroll
        for (int ct = 0; ct < 2; ++ct) {
            int c = w*32 + ct*16 + lr;
            float a1c = a1[c], a2c = a2[c];
            bf16x4 wv;
#pragma unroll
            for (int g = 0; g < 4; ++g) {
                float v = acc[rt][ct][g];
                wv[g] = f2bf(v);
                p1[g] += v * a1c;
                p2[g] += v * a2c;
            }
            int r0 = rows0 + rt*16 + lg*4;
            size_t off = (size_t)(r0 >> 6) * 8192 + (size_t)(c >> 4) * 1024
                       + (size_t)((r0 >> 5) & 1) * 512 + (size_t)(c & 15) * 32
                       + (size_t)((r0 >> 3) & 3) * 8 + (size_t)(r0 & 7);
            *(bf16x4*)(WhT + off) = wv;
        }
#pragma unroll
        for (int off = 1; off < 16; off <<= 1) {
#pragma unroll
            for (int g = 0; g < 4; ++g) {
                p1[g] += __shfl_xor(p1[g], off);
                p2[g] += __shfl_xor(p2[g], off);
            }
        }
        if (lr == 0) {
            int rloc = rt*16 + lg*4;
#pragma unroll
            for (int g = 0; g < 4; ++g) {
                atomicAdd(&s_lds[0][rloc+g], p1[g]);
                atomicAdd(&s_lds[1][rloc+g], p2[g]);
            }
        }
    }
    __syncthreads();
    if (t < 32)       s1g[rows0 + t]        = s_lds[0][t];
    else if (t < 64)  s2g[rows0 + (t - 32)] = s_lds[1][t - 32];
}

// k2: block = 4 waves on the SAME 16 rows, in-block j-split x4, cross-block x S.
// Per iteration: (1) issue B-tile loads (contiguous 16KB, coalesced 1KB each),
// (2) exp/mask from prefetched adj + LDS-resident s2, P->LDS, (3) prefetch next
// adj (CACHED - adj is L3-resident across timed replays), (4) A-frags from LDS,
// (5) MFMA drains B. No barriers in the main loop.
__global__ __launch_bounds__(256, 3) void k2_main(
        const int* __restrict__ adj, const short* __restrict__ WhT,
        const float* __restrict__ s1g, const float* __restrict__ s2g,
        float* __restrict__ numP, float* __restrict__ zP,
        int S, int npb) {
    __shared__ __attribute__((aligned(16))) char smem[18432 + 8192 + 64];
    short* Pl   = (short*)smem;                   // [4][2][16][72]
    float* Lacc = (float*)smem;                   // [2][2048], aliases Pl
    float* s2l  = (float*)(smem + 18432);         // [2048] block's s2 slice
    float* Lz   = (float*)(smem + 18432 + 8192);  // [16]
#define PL(W_,D_,R_) (Pl + (((W_)*2 + (D_))*16 + (R_))*72)

    int t = threadIdx.x, w = t >> 6, l = t & 63;
    int lo = l & 15, hi = l >> 4;     // used for both stage and fragment sides
    int b = blockIdx.x, jseg = b % S, rg = b / S;
    int rows0 = rg << 4;
    int j0 = jseg * npb;

    // stage s2 slice + init Lz
    { f32x4* d_ = (f32x4*)s2l; const f32x4* s_ = (const f32x4*)(s2g + j0);
      d_[t] = s_[t]; d_[t + 256] = s_[t + 256]; }
    if (t < 16) Lz[t] = 0.0f;
    __syncthreads();

    int nwt = npb >> 2;               // j span per wave
    int jb  = j0 + w * nwt;
    int NT  = nwt >> 6;

    float s1q[4];
#pragma unroll
    for (int c = 0; c < 4; ++c) s1q[c] = s1g[rows0 + c*4 + hi];

    f32x4 acc[8] = {};
    float zacc[4] = {0.f, 0.f, 0.f, 0.f};

    // adj prefetch: instr c reads rows rows0+c*4+hi, cols jt+lo*4 (4x256B runs)
    i32x4 A[4];
#pragma unroll
    for (int c = 0; c < 4; ++c)
        A[c] = *(const i32x4*)(adj + (size_t)(rows0 + c*4 + hi) * NROW + jb + lo*4);

    int d = 0;
    for (int it = 0; it < NT; ++it) {
        int jt = jb + (it << 6);
        // --- (1) B tile: 16 coalesced 1KB loads, contiguous 16KB ---
        bf16x8 Bv[8][2];
        const short* tb = WhT + (size_t)(jt >> 6) * 8192 + lo*32 + hi*8;
#pragma unroll
        for (int ct = 0; ct < 8; ++ct) {
            Bv[ct][0] = *(const bf16x8*)(tb + ct*1024);
            Bv[ct][1] = *(const bf16x8*)(tb + ct*1024 + 512);
        }
        // --- (2) exp/mask (prefetched adj, s2 from LDS), bf16 P -> LDS ---
        int jloc = jt - j0;
        f32x4 sv = *(const f32x4*)(s2l + jloc + lo*4);
#pragma unroll
        for (int c = 0; c < 4; ++c) {
            bf16x4 pv;
#pragma unroll
            for (int e = 0; e < 4; ++e) {
                float x  = s1q[c] + sv[e];
                float lk = fmaxf(x, 0.2f * x);
                float p  = __expf(lk);
                p = (A[c][e] > 0) ? p : 0.0f;
                zacc[c] += p;
                pv[e] = f2bf(p);
            }
            *(bf16x4*)(PL(w, d, c*4 + hi) + lo*4) = pv;
        }
        // --- (3) prefetch next adj tile ---
        if (it + 1 < NT) {
#pragma unroll
            for (int c = 0; c < 4; ++c)
                A[c] = *(const i32x4*)(adj + (size_t)(rows0 + c*4 + hi) * NROW + jt + 64 + lo*4);
        }
        // --- (4) A-frags from LDS (same-wave RAW) ---
        const short* Pr = PL(w, d, lo);
        bf16x8 fa0 = *(const bf16x8*)(Pr + hi*8);
        bf16x8 fa1 = *(const bf16x8*)(Pr + 32 + hi*8);
        // --- (5) MFMA drains B ---
#pragma unroll
        for (int ct = 0; ct < 8; ++ct) {
            acc[ct] = __builtin_amdgcn_mfma_f32_16x16x32_bf16(fa0, Bv[ct][0], acc[ct], 0, 0, 0);
            acc[ct] = __builtin_amdgcn_mfma_f32_16x16x32_bf16(fa1, Bv[ct][1], acc[ct], 0, 0, 0);
        }
        d ^= 1;
    }

    // --- z: reduce over the 16 lo-lanes (cols), rows = c*4+hi ---
#pragma unroll
    for (int c = 0; c < 4; ++c) {
        zacc[c] += __shfl_xor(zacc[c], 1);
        zacc[c] += __shfl_xor(zacc[c], 2);
        zacc[c] += __shfl_xor(zacc[c], 4);
        zacc[c] += __shfl_xor(zacc[c], 8);
    }
    if (lo == 0) {
#pragma unroll
        for (int c = 0; c < 4; ++c) atomicAdd(&Lz[c*4 + hi], zacc[c]);
    }
    __syncthreads();   // also separates last Pl reads from Lacc writes (alias!)
    if (t < 16) zP[(size_t)jseg * NROW + rows0 + t] = Lz[t];

    // --- acc: tree-reduce 4 waves (identical (lane,ct,g)->(row,col) maps) ---
    if (w >= 2) {
        float* s0 = &Lacc[(w - 2) * 2048];
#pragma unroll
        for (int ct = 0; ct < 8; ++ct) *(f32x4*)(s0 + ct*256 + l*4) = acc[ct];
    }
    __syncthreads();
    if (w < 2) {
        const float* s0 = &Lacc[w * 2048];
#pragma unroll
        for (int ct = 0; ct < 8; ++ct) acc[ct] += *(const f32x4*)(s0 + ct*256 + l*4);
    }
    __syncthreads();
    if (w == 1) {
        float* s0 = &Lacc[0];
#pragma unroll
        for (int ct = 0; ct < 8; ++ct) *(f32x4*)(s0 + ct*256 + l*4) = acc[ct];
    }
    __syncthreads();
    if (w == 0) {
        const float* s0 = &Lacc[0];
        size_t obase = (size_t)jseg * NROW * NF;
#pragma unroll
        for (int ct = 0; ct < 8; ++ct) {
            acc[ct] += *(const f32x4*)(s0 + ct*256 + l*4);
            int cc = ct*16 + lo;
            int r0 = rows0 + hi*4;
#pragma unroll
            for (int g = 0; g < 4; ++g)
                numP[obase + (size_t)(r0 + g) * NF + cc] = acc[ct][g];
        }
    }
#undef PL
}

// k3: out = elu( sum_s num / sum_s z ), vectorized x4
__global__ __launch_bounds__(256) void k3_reduce(const float* __restrict__ numP,
        const float* __restrict__ zP, float* __restrict__ out, int S) {
    int idx = (blockIdx.x * 256 + threadIdx.x) * 4;
    int r = idx >> 7;
    f32x4 num = {};
    float zz = 0.0f;
    for (int s = 0; s < S; ++s) {
        f32x4 v = *(const f32x4*)(numP + (size_t)s * (NROW * NF) + idx);
        num += v;
        zz  += zP[s * NROW + r];
    }
    f32x4 o;
#pragma unroll
    for (int e = 0; e < 4; ++e) {
        float h = num[e] / zz;
        o[e] = (h > 0.0f) ? h : expm1f(h);
    }
    *(f32x4*)(out + idx) = o;
}

extern "C" void kernel_launch(void* const* d_in, const int* in_sizes, int n_in,
                              void* d_out, int out_size, void* d_ws, size_t ws_size,
                              hipStream_t stream) {
    const float* mo  = (const float*)d_in[0];
    const int*   adj = (const int*)d_in[1];
    const float* W   = (const float*)d_in[2];
    const float* a1  = (const float*)d_in[3];
    const float* a2  = (const float*)d_in[4];
    float* out = (float*)d_out;

    char* p = (char*)d_ws;
    short* WT  = (short*)p;  p += (size_t)NF * NF * 2;
    short* WhT = (short*)p;  p += (size_t)NF * NROW * 2;
    float* s1  = (float*)p;  p += (size_t)NROW * 4;
    float* s2  = (float*)p;  p += (size_t)NROW * 4;
    float* zP  = (float*)p;  p += (size_t)4 * NROW * 4;   // reserved for S<=4
    size_t fixed = (size_t)(p - (char*)d_ws);

    int S = 4;
    while (S > 1 && fixed + (size_t)S * NROW * NF * 4 > ws_size) S >>= 1;
    float* numP = (float*)p;
    if (fixed + (size_t)S * NROW * NF * 4 > ws_size) numP = out;  // S==1 in-place fallback

    k0_wt<<<dim3(64), dim3(256), 0, stream>>>(W, WT);
    k1_wh<<<dim3(256), dim3(256), 0, stream>>>(mo, WT, a1, a2, WhT, s1, s2);
    k2_main<<<dim3((NROW / 16) * S), dim3(256), 0, stream>>>(adj, WhT, s1, s2, numP, zP, S, NROW / S);
    k3_reduce<<<dim3(NROW * NF / 1024), dim3(256), 0, stream>>>(numP, zP, out, S);
}